// Round 1
// 8664.820 us; speedup vs baseline: 1.0177x; 1.0177x over previous
//
#include <hip/hip_runtime.h>

// RnnTagger (f32 in / f32 out): tokens[64*512] i32; emb[50000,256]; W_ih[1536,256];
// W_hh[1536,512]; b_ih[1536]; b_hh[1536]; W_tag[64,512]; b_tag[64].
// d_out f32: tag_logits [64,512,64] then preds [64,512] flat.
//
// f32-faithful MFMA via f16 double-split: x ~= hi + lo/4096 (hi,lo f16); product
// = 3 f16 MFMAs (m += Ah*Wh; s += Al*Wh + Ah*Wl; result = m + s/4096).
//
// R7: kill the poll storm. R6 polled 8192 tagged atoms/WG/round against a 512KB
// region through the coherent (L2-bypassing) path -> L3-slice hotspot, 17us/step
// with MfmaUtil 1%. R7 sync protocol:
//  - producer: payload atomic stores -> __syncthreads (drains vmcnt(0), stores
//    are at the coherence point) -> tid0 stores flag=t+1 (relaxed, agent)
//  - consumer: gi MFMAs first, then each thread spins on ONE 4B flag
//    (flags[cluster][tid&7], 128B-padded) with s_sleep backoff, __syncthreads
//    to conjoin all 8 producers, then ONE bulk payload load + tag verify
//    (tags kept as a safety net; retry loop should never fire)
//  - optimistic pre-load dropped (was guaranteed-stale 2MB/step of traffic)
//  - st stores + x-publish moved after the flag store (off the critical path)
// Flags live in d_out's preds region (scratch during gru_rec; tag_argmax
// overwrites every preds element afterwards). Zeroed by init_ws each launch.
//
// ws (72,482,816 B, same layout as R5/R6):
//   [0,+524288)         h tagged dbuf  u64[2][64][512]
//   [524288,+3145728)   whh2  [hi/lo][1536][512] f16
//   [3670016,+1572864)  wih2  [hi/lo][1536][256] f16
//   [5242880,+131072)   wtag2 [hi/lo][64][512] f16
//   [5373952,+67108864) st    [b*512+t][512] f32

typedef unsigned short ushortT;
typedef unsigned long long u64c;
typedef float f32x4 __attribute__((ext_vector_type(4)));
typedef _Float16 f16x8 __attribute__((ext_vector_type(8)));
typedef unsigned int u32x4 __attribute__((ext_vector_type(4)));

#define MFMAH(a, b, c) __builtin_amdgcn_mfma_f32_16x16x32_f16((a), (b), (c), 0, 0, 0)
#define KSC (1.0f / 4096.0f)

__device__ __forceinline__ void splitf(float x, ushortT& hi, ushortT& lo) {
    _Float16 h = (_Float16)x;
    float r = x - (float)h;
    _Float16 l = (_Float16)(r * 4096.0f);
    hi = __builtin_bit_cast(ushortT, h);
    lo = __builtin_bit_cast(ushortT, l);
}

// ---------- k0: split weights into f16 hi/lo planes ----------
__global__ __launch_bounds__(256) void split_weights(
    const float* __restrict__ Whh, const float* __restrict__ Wih,
    const float* __restrict__ Wtag, ushortT* __restrict__ wh2,
    ushortT* __restrict__ wi2, ushortT* __restrict__ wt2)
{
    const int i = blockIdx.x * 256 + threadIdx.x;
    ushortT hi, lo;
    if (i < 786432) {                       // 1536*512
        splitf(Whh[i], hi, lo);
        wh2[i] = hi; wh2[786432 + i] = lo;
    } else if (i < 786432 + 393216) {       // 1536*256
        const int j = i - 786432;
        splitf(Wih[j], hi, lo);
        wi2[j] = hi; wi2[393216 + j] = lo;
    } else if (i < 786432 + 393216 + 32768) {   // 64*512
        const int j = i - 786432 - 393216;
        splitf(Wtag[j], hi, lo);
        wt2[j] = hi; wt2[32768 + j] = lo;
    }
}

// ---------- k1: zero tagged h double buffer (tag 0 = "after step -1") + flags ----------
__global__ void init_ws(uint4* p, uint4* f) {
    int i = blockIdx.x * blockDim.x + threadIdx.x;
    uint4 z; z.x = 0u; z.y = 0u; z.z = 0u; z.w = 0u;
    if (i < 32768) p[i] = z;    // 524288 B / 16
    if (i < 256)   f[i] = z;    // 4096 B of flags
}

// ---------- k2: fused gi + serial GRU recurrence ----------
// 32 WGs x 256. cluster = bid>>3 owns batch rows [cluster*16,+16); jg = bid&7
// owns h-cols [jg*64,+64); wave owns 16 cols (all 3 gates).
__global__ __launch_bounds__(256, 1) void gru_rec(
    const int* __restrict__ tok, const float* __restrict__ emb,
    const ushortT* __restrict__ wih2, const ushortT* __restrict__ whh2,
    const float* __restrict__ bih, const float* __restrict__ bhh,
    u64c* __restrict__ hbt, float* __restrict__ st,
    unsigned* __restrict__ flags)
{
    __shared__ ushortT xl[2][2][16][264];   // x dbuf: [buf][hi/lo][16 b][256k pad]
    __shared__ unsigned hl[8256];           // packed h tile [16 rows][512 + pad 4]

    const int bid = blockIdx.x;
    const int cluster = bid >> 3;
    const int jg = bid & 7;
    const int tid = threadIdx.x;
    const int wave = tid >> 6;
    const int lane = tid & 63;
    const int ln = lane & 15, quad = lane >> 4;
    const int m0 = cluster * 16;
    const int j_lane = jg * 64 + wave * 16 + ln;

    // 128B-padded flags: flags[(cluster*8 + jg)*32]. Each thread polls ONE
    // producer's flag (tid&7); barrier conjoins all 8.
    unsigned* pollp = flags + (unsigned)(cluster * 8 + (tid & 7)) * 32u;
    unsigned* ownp  = flags + (unsigned)(cluster * 8 + jg) * 32u;

    const float c_r  = bih[j_lane]        + bhh[j_lane];
    const float c_z  = bih[512 + j_lane]  + bhh[512 + j_lane];
    const float bi_n = bih[1024 + j_lane];
    const float bh_n = bhh[1024 + j_lane];

    // Prologue: stage x_0 (split f16 hi/lo) into LDS buf 0.
    const int xr = tid >> 4, xc = (tid & 15) * 16;
    {
        const int token = tok[(m0 + xr) * 512];
        const float* xsrc = emb + (size_t)token * 256 + xc;
#pragma unroll
        for (int i = 0; i < 16; ++i) {
            ushortT hi, lo; splitf(xsrc[i], hi, lo);
            xl[0][0][xr][xc + i] = hi; xl[0][1][xr][xc + i] = lo;
        }
    }
    __syncthreads();

    float hprev[4] = {0.f, 0.f, 0.f, 0.f};

    for (int t = 0; t < 512; ++t) {
        const int rb = t & 1;
        const int wb = rb ^ 1;
        u64c* tile = hbt + (size_t)rb * 32768 + (size_t)m0 * 512;

        // (B) x_{t+1} global loads into regs (published to LDS in phase H)
        const int tp = (t + 1) & 511;
        const int xtoken = tok[(m0 + xr) * 512 + tp];
        const float* xsrc = emb + (size_t)xtoken * 256 + xc;
        f32x4 xv[4];
#pragma unroll
        for (int i = 0; i < 4; ++i)
            xv[i] = *reinterpret_cast<const f32x4*>(xsrc + i * 4);

        // accumulators: r,z combine gi+gh; n separate (needs r * gh_n)
        f32x4 m_r = (f32x4){0.f,0.f,0.f,0.f}, s_r = (f32x4){0.f,0.f,0.f,0.f};
        f32x4 m_z = (f32x4){0.f,0.f,0.f,0.f}, s_z = (f32x4){0.f,0.f,0.f,0.f};
        f32x4 m_gin = (f32x4){0.f,0.f,0.f,0.f}, s_gin = (f32x4){0.f,0.f,0.f,0.f};
        f32x4 m_ghn = (f32x4){0.f,0.f,0.f,0.f}, s_ghn = (f32x4){0.f,0.f,0.f,0.f};

        // (C) gi = x_t @ W_ih^T (independent of h; runs while partners finish)
#pragma unroll
        for (int ks = 0; ks < 8; ++ks) {
            const int k = ks * 32 + quad * 8;
            f16x8 Axh = *reinterpret_cast<const f16x8*>(&xl[rb][0][ln][k]);
            f16x8 Axl = *reinterpret_cast<const f16x8*>(&xl[rb][1][ln][k]);
#pragma unroll
            for (int g = 0; g < 3; ++g) {
                const ushortT* wr = wih2 + (size_t)(g * 512 + j_lane) * 256 + k;
                f16x8 Wh = *reinterpret_cast<const f16x8*>(wr);
                f16x8 Wl = *reinterpret_cast<const f16x8*>(wr + 393216);
                if (g == 0) {
                    m_r = MFMAH(Axh, Wh, m_r);
                    s_r = MFMAH(Axl, Wh, s_r);
                    s_r = MFMAH(Axh, Wl, s_r);
                } else if (g == 1) {
                    m_z = MFMAH(Axh, Wh, m_z);
                    s_z = MFMAH(Axl, Wh, s_z);
                    s_z = MFMAH(Axh, Wl, s_z);
                } else {
                    m_gin = MFMAH(Axh, Wh, m_gin);
                    s_gin = MFMAH(Axl, Wh, s_gin);
                    s_gin = MFMAH(Axh, Wl, s_gin);
                }
            }
        }

        // (D0) flag wait: one 4B address per thread, backoff spin
        {
            const unsigned want = (unsigned)t;
            unsigned f = __hip_atomic_load(pollp, __ATOMIC_RELAXED,
                                           __HIP_MEMORY_SCOPE_AGENT);
            while (f < want) {
                __builtin_amdgcn_s_sleep(2);
                f = __hip_atomic_load(pollp, __ATOMIC_RELAXED,
                                      __HIP_MEMORY_SCOPE_AGENT);
            }
        }
        __syncthreads();   // all 8 producer flags confirmed across the WG

        // (A) one bulk cooperative payload load: 32 atoms/thread, coalesced
        u64c v[32];
#pragma unroll
        for (int j = 0; j < 32; ++j)
            v[j] = __hip_atomic_load(tile + tid + 256 * j,
                                     __ATOMIC_RELAXED, __HIP_MEMORY_SCOPE_AGENT);

        // (D1) tag verify — safety net only; should pass first try
        const unsigned etag = (unsigned)t;
        for (;;) {
            bool ok = true;
#pragma unroll
            for (int j = 0; j < 32; ++j) ok &= ((unsigned)(v[j] >> 32) == etag);
            if (__all(ok)) break;
            __builtin_amdgcn_s_sleep(4);
#pragma unroll
            for (int j = 0; j < 32; ++j)
                v[j] = __hip_atomic_load(tile + tid + 256 * j,
                                         __ATOMIC_RELAXED, __HIP_MEMORY_SCOPE_AGENT);
        }

        // (E) publish packed payloads to LDS tile
#pragma unroll
        for (int j = 0; j < 32; ++j) {
            const int a = tid + 256 * j;
            hl[(a >> 9) * 516 + (a & 511)] = (unsigned)v[j];
        }
        __syncthreads();

        // (F) gh = h_{t-1} @ W_hh^T : A-frags from LDS, W streamed from L2
#pragma unroll
        for (int ks = 0; ks < 16; ++ks) {
            const int k = ks * 32 + quad * 8;
            const unsigned* hp = &hl[ln * 516 + k];
            u32x4 q0 = *reinterpret_cast<const u32x4*>(hp);
            u32x4 q1 = *reinterpret_cast<const u32x4*>(hp + 4);
            u32x4 ah, al;
#pragma unroll
            for (int i = 0; i < 2; ++i) {
                ah[i]   = (q0[2*i] & 0xffffu) | (q0[2*i+1] << 16);
                al[i]   = (q0[2*i] >> 16)     | (q0[2*i+1] & 0xffff0000u);
                ah[2+i] = (q1[2*i] & 0xffffu) | (q1[2*i+1] << 16);
                al[2+i] = (q1[2*i] >> 16)     | (q1[2*i+1] & 0xffff0000u);
            }
            f16x8 Ah = __builtin_bit_cast(f16x8, ah);
            f16x8 Al = __builtin_bit_cast(f16x8, al);
#pragma unroll
            for (int g = 0; g < 3; ++g) {
                const ushortT* wr = whh2 + (size_t)(g * 512 + j_lane) * 512 + k;
                f16x8 Wh = *reinterpret_cast<const f16x8*>(wr);
                f16x8 Wl = *reinterpret_cast<const f16x8*>(wr + 786432);
                if (g == 0) {
                    m_r = MFMAH(Ah, Wh, m_r);
                    s_r = MFMAH(Al, Wh, s_r);
                    s_r = MFMAH(Ah, Wl, s_r);
                } else if (g == 1) {
                    m_z = MFMAH(Ah, Wh, m_z);
                    s_z = MFMAH(Al, Wh, s_z);
                    s_z = MFMAH(Ah, Wl, s_z);
                } else {
                    m_ghn = MFMAH(Ah, Wh, m_ghn);
                    s_ghn = MFMAH(Al, Wh, s_ghn);
                    s_ghn = MFMAH(Ah, Wl, s_ghn);
                }
            }
        }

        // (G) gates + h_new; tagged h stores, then barrier-drained flag publish
        u64c* hw = hbt + (size_t)wb * 32768;
        const u64c ntag = ((u64c)(unsigned)(t + 1)) << 32;
        float hn4[4];
#pragma unroll
        for (int r4 = 0; r4 < 4; ++r4) {
            const float pre_r = m_r[r4] + s_r[r4] * KSC + c_r;
            const float pre_z = m_z[r4] + s_z[r4] * KSC + c_z;
            const float gin   = m_gin[r4] + s_gin[r4] * KSC + bi_n;
            const float ghn   = m_ghn[r4] + s_ghn[r4] * KSC + bh_n;
            const float rr = 1.f / (1.f + expf(-pre_r));
            const float zz = 1.f / (1.f + expf(-pre_z));
            const float nn = tanhf(gin + rr * ghn);
            const float hn = (1.f - zz) * nn + zz * hprev[r4];
            hprev[r4] = hn;
            hn4[r4] = hn;
            ushortT hi, lo; splitf(hn, hi, lo);
            const unsigned pk = (unsigned)hi | ((unsigned)lo << 16);
            const int b = m0 + quad * 4 + r4;
            __hip_atomic_store(&hw[b * 512 + j_lane], ntag | (u64c)pk,
                               __ATOMIC_RELAXED, __HIP_MEMORY_SCOPE_AGENT);
        }

        // barrier drains vmcnt(0) per thread -> all payload stores are at the
        // coherence point before the flag goes out
        __syncthreads();
        if (tid == 0)
            __hip_atomic_store(ownp, (unsigned)(t + 1),
                               __ATOMIC_RELAXED, __HIP_MEMORY_SCOPE_AGENT);

        // st stores — consumed only by k3 after this kernel; off critical path
#pragma unroll
        for (int r4 = 0; r4 < 4; ++r4) {
            const int b = m0 + quad * 4 + r4;
            st[((size_t)b * 512 + t) * 512 + j_lane] = hn4[r4];
        }

        // (H) publish x_{t+1} into LDS buffer wb
#pragma unroll
        for (int i = 0; i < 16; ++i) {
            ushortT hi, lo; splitf(xv[i >> 2][i & 3], hi, lo);
            xl[wb][0][xr][xc + i] = hi; xl[wb][1][xr][xc + i] = lo;
        }
        __syncthreads();   // xl + hl turnover
    }
}

// ---------- k3: tag logits + argmax + PAD mask (R5-identical) ----------
__global__ __launch_bounds__(256) void tag_argmax(
    const float* __restrict__ st, const ushortT* __restrict__ wtag2,
    const float* __restrict__ btag, const int* __restrict__ tok,
    float* __restrict__ out)
{
    const int wave = threadIdx.x >> 6;
    const int lane = threadIdx.x & 63;
    const int ln = lane & 15, quad = lane >> 4;
    const int mt = blockIdx.x * 4 + wave;   // 0..2047

    const float* arow = st + (size_t)(mt * 16 + ln) * 512;
    f32x4 am[4], as_[4];
#pragma unroll
    for (int ti = 0; ti < 4; ++ti) { am[ti] = (f32x4){0.f,0.f,0.f,0.f}; as_[ti] = (f32x4){0.f,0.f,0.f,0.f}; }

#pragma unroll
    for (int ks = 0; ks < 16; ++ks) {
        const int k = ks * 32 + quad * 8;
        f16x8 Ah, Al;
#pragma unroll
        for (int e = 0; e < 8; ++e) {
            const float x = arow[k + e];
            _Float16 h = (_Float16)x;
            Ah[e] = h;
            Al[e] = (_Float16)((x - (float)h) * 4096.0f);
        }
#pragma unroll
        for (int ti = 0; ti < 4; ++ti) {
            const ushortT* wr = wtag2 + (size_t)(ti * 16 + ln) * 512 + k;
            f16x8 Wh = *reinterpret_cast<const f16x8*>(wr);
            f16x8 Wl = *reinterpret_cast<const f16x8*>(wr + 32768);
            am[ti]  = MFMAH(Ah, Wh, am[ti]);
            as_[ti] = MFMAH(Ah, Wl, as_[ti]);
            as_[ti] = MFMAH(Al, Wh, as_[ti]);
        }
    }

    float vals[4][4];
#pragma unroll
    for (int ti = 0; ti < 4; ++ti) {
        const float bb = btag[ti * 16 + ln];
#pragma unroll
        for (int r = 0; r < 4; ++r) vals[ti][r] = am[ti][r] + as_[ti][r] * KSC + bb;
    }
#pragma unroll
    for (int ti = 0; ti < 4; ++ti)
#pragma unroll
        for (int r = 0; r < 4; ++r) {
            const int row = mt * 16 + quad * 4 + r;
            out[(size_t)row * 64 + ti * 16 + ln] = vals[ti][r];
        }
#pragma unroll
    for (int r = 0; r < 4; ++r) {
        float best = vals[0][r];
        int bc = ln;
#pragma unroll
        for (int ti = 1; ti < 4; ++ti) {
            const float v = vals[ti][r];
            const int c = ti * 16 + ln;
            if (v > best) { best = v; bc = c; }
        }
        for (int off = 1; off < 16; off <<= 1) {
            const float ov = __shfl_xor(best, off);
            const int oc = __shfl_xor(bc, off);
            if (ov > best || (ov == best && oc < bc)) { best = ov; bc = oc; }
        }
        if (ln == 0) {
            const int row = mt * 16 + quad * 4 + r;   // = b*512+t = token idx
            const int token = tok[row];
            const int pred = (token != 0) ? bc : 0;
            out[2097152 + (size_t)row] = (float)pred;
        }
    }
}

extern "C" void kernel_launch(void* const* d_in, const int* in_sizes, int n_in,
                              void* d_out, int out_size, void* d_ws, size_t ws_size,
                              hipStream_t stream) {
    const int*   tokens = (const int*)d_in[0];
    const float* emb    = (const float*)d_in[1];
    const float* Wih    = (const float*)d_in[2];
    const float* Whh    = (const float*)d_in[3];
    const float* bih    = (const float*)d_in[4];
    const float* bhh    = (const float*)d_in[5];
    const float* Wtag   = (const float*)d_in[6];
    const float* btag   = (const float*)d_in[7];

    char* ws = (char*)d_ws;
    u64c*     hbt   = (u64c*)ws;                     // 524,288 B
    ushortT*  whh2  = (ushortT*)(ws + 524288);       // 3,145,728 B
    ushortT*  wih2  = (ushortT*)(ws + 3670016);      // 1,572,864 B
    ushortT*  wtag2 = (ushortT*)(ws + 5242880);      // 131,072 B
    float*    stf   = (float*)(ws + 5373952);        // 67,108,864 B (total 72.48 MB)
    float*    out   = (float*)d_out;

    // Sync flags live in d_out's preds region (scratch during gru_rec;
    // tag_argmax rewrites every preds element afterwards). 32 flags, 128B pad.
    unsigned* flags = (unsigned*)(out + 2097152);

    split_weights<<<4736, 256, 0, stream>>>(Whh, Wih, Wtag, whh2, wih2, wtag2);
    init_ws<<<128, 256, 0, stream>>>((uint4*)ws, (uint4*)flags);
    gru_rec<<<32, 256, 0, stream>>>(tokens, emb, wih2, whh2, bih, bhh, hbt, stf, flags);
    tag_argmax<<<512, 256, 0, stream>>>(stf, wtag2, btag, tokens, out);
}

// Round 2
// 7312.090 us; speedup vs baseline: 1.2060x; 1.1850x over previous
//
#include <hip/hip_runtime.h>

// RnnTagger (f32 in / f32 out): tokens[64*512] i32; emb[50000,256]; W_ih[1536,256];
// W_hh[1536,512]; b_ih[1536]; b_hh[1536]; W_tag[64,512]; b_tag[64].
// d_out f32: tag_logits [64,512,64] then preds [64,512] flat.
//
// f32-faithful MFMA via f16 double-split: x ~= hi + lo/4096 (hi,lo f16); product
// = 3 f16 MFMAs (m += Ah*Wh; s += Al*Wh + Ah*Wl; result = m + s/4096).
//
// R8: occupancy fix. R7 counters: 1 wave/SIMD (Occ 1.55% = 128 waves, VGPR 256,
// 32 WGs on 32 CUs) -> every W-stream / payload latency stalls its SIMD dead;
// per-active-CU busy only ~3.5us of the 17us step. R8 uses 512-thread WGs
// (8 waves on one CU = 2 waves/SIMD GUARANTEED) with wave pairs (w, w+4)
// K-SPLITTING the gi/gh reductions over the same output cols:
//   - lower wave w: gi ks 0..3, gh ks 0..7
//   - upper wave w+4: gi ks 4..7, gh ks 8..15, plus x prefetch/publish
//   - partials combined via f32x4-interleaved LDS (conflict-free b128)
//   - lower waves do gates + tagged h stores + st stores
// Per-CU W bytes, MFMA and VALU totals unchanged vs R7; latencies now overlap
// across the two waves per SIMD. Sync protocol (tagged atoms + per-producer
// flags in d_out's preds region) unchanged from R7.
//
// ws (72,482,816 B, same layout as R5-R7):
//   [0,+524288)         h tagged dbuf  u64[2][64][512]
//   [524288,+3145728)   whh2  [hi/lo][1536][512] f16
//   [3670016,+1572864)  wih2  [hi/lo][1536][256] f16
//   [5242880,+131072)   wtag2 [hi/lo][64][512] f16
//   [5373952,+67108864) st    [b*512+t][512] f32

typedef unsigned short ushortT;
typedef unsigned long long u64c;
typedef float f32x4 __attribute__((ext_vector_type(4)));
typedef _Float16 f16x8 __attribute__((ext_vector_type(8)));
typedef unsigned int u32x4 __attribute__((ext_vector_type(4)));

#define MFMAH(a, b, c) __builtin_amdgcn_mfma_f32_16x16x32_f16((a), (b), (c), 0, 0, 0)
#define KSC (1.0f / 4096.0f)

__device__ __forceinline__ void splitf(float x, ushortT& hi, ushortT& lo) {
    _Float16 h = (_Float16)x;
    float r = x - (float)h;
    _Float16 l = (_Float16)(r * 4096.0f);
    hi = __builtin_bit_cast(ushortT, h);
    lo = __builtin_bit_cast(ushortT, l);
}

// ---------- k0: split weights into f16 hi/lo planes ----------
__global__ __launch_bounds__(256) void split_weights(
    const float* __restrict__ Whh, const float* __restrict__ Wih,
    const float* __restrict__ Wtag, ushortT* __restrict__ wh2,
    ushortT* __restrict__ wi2, ushortT* __restrict__ wt2)
{
    const int i = blockIdx.x * 256 + threadIdx.x;
    ushortT hi, lo;
    if (i < 786432) {                       // 1536*512
        splitf(Whh[i], hi, lo);
        wh2[i] = hi; wh2[786432 + i] = lo;
    } else if (i < 786432 + 393216) {       // 1536*256
        const int j = i - 786432;
        splitf(Wih[j], hi, lo);
        wi2[j] = hi; wi2[393216 + j] = lo;
    } else if (i < 786432 + 393216 + 32768) {   // 64*512
        const int j = i - 786432 - 393216;
        splitf(Wtag[j], hi, lo);
        wt2[j] = hi; wt2[32768 + j] = lo;
    }
}

// ---------- k1: zero tagged h double buffer (tag 0 = "after step -1") + flags ----------
__global__ void init_ws(uint4* p, uint4* f) {
    int i = blockIdx.x * blockDim.x + threadIdx.x;
    uint4 z; z.x = 0u; z.y = 0u; z.z = 0u; z.w = 0u;
    if (i < 32768) p[i] = z;    // 524288 B / 16
    if (i < 256)   f[i] = z;    // 4096 B of flags
}

// ---------- k2: fused gi + serial GRU recurrence ----------
// 32 WGs x 512 (8 waves = 2 waves/SIMD). cluster = bid>>3 owns batch rows
// [cluster*16,+16); jg = bid&7 owns h-cols [jg*64,+64). Wave pair (w, w+4)
// owns cols jg*64 + w*16 + [0,16), K-split across the pair.
__global__ __launch_bounds__(512, 1) void gru_rec(
    const int* __restrict__ tok, const float* __restrict__ emb,
    const ushortT* __restrict__ wih2, const ushortT* __restrict__ whh2,
    const float* __restrict__ bih, const float* __restrict__ bhh,
    u64c* __restrict__ hbt, float* __restrict__ st,
    unsigned* __restrict__ flags)
{
    __shared__ ushortT xl[2][2][16][264];   // 33792 B: x dbuf [buf][hi/lo][16 b][256k pad]
    __shared__ unsigned hl[8256];           // 33024 B: packed h tile [16 rows][512 + pad 4]
    __shared__ f32x4 pl[4][8][64];          // 32768 B: upper-wave partials [u][vec][lane]

    const int bid = blockIdx.x;
    const int cluster = bid >> 3;
    const int jg = bid & 7;
    const int tid = threadIdx.x;
    const int wave = tid >> 6;
    const int lane = tid & 63;
    const int wl = wave & 3;                // pair column-slot 0..3
    const bool upper = wave >= 4;
    const int ln = lane & 15, quad = lane >> 4;
    const int m0 = cluster * 16;
    const int j_lane = jg * 64 + wl * 16 + ln;

    // 128B-padded flags: flags[(cluster*8 + jg)*32]; threads 0..7 poll.
    unsigned* ownp = flags + (unsigned)(cluster * 8 + jg) * 32u;

    const float c_r  = bih[j_lane]        + bhh[j_lane];
    const float c_z  = bih[512 + j_lane]  + bhh[512 + j_lane];
    const float bi_n = bih[1024 + j_lane];
    const float bh_n = bhh[1024 + j_lane];

    // Prologue: upper 256 threads stage x_0 into LDS buf 0.
    const int xr = (tid & 255) >> 4, xc = (tid & 15) * 16;
    if (upper) {
        const int token = tok[(m0 + xr) * 512];
        const float* xsrc = emb + (size_t)token * 256 + xc;
#pragma unroll
        for (int i = 0; i < 16; ++i) {
            ushortT hi, lo; splitf(xsrc[i], hi, lo);
            xl[0][0][xr][xc + i] = hi; xl[0][1][xr][xc + i] = lo;
        }
    }
    __syncthreads();

    float hprev[4] = {0.f, 0.f, 0.f, 0.f};

    for (int t = 0; t < 512; ++t) {
        const int rb = t & 1;
        const int wb = rb ^ 1;
        u64c* tile = hbt + (size_t)rb * 32768 + (size_t)m0 * 512;

        // (B) upper: x_{t+1} global loads into regs (published in phase H)
        f32x4 xv[4];
        if (upper) {
            const int tp = (t + 1) & 511;
            const int xtoken = tok[(m0 + xr) * 512 + tp];
            const float* xsrc = emb + (size_t)xtoken * 256 + xc;
#pragma unroll
            for (int i = 0; i < 4; ++i)
                xv[i] = *reinterpret_cast<const f32x4*>(xsrc + i * 4);
        }

        // per-pair partial accumulators
        f32x4 m_r = (f32x4){0.f,0.f,0.f,0.f}, s_r = (f32x4){0.f,0.f,0.f,0.f};
        f32x4 m_z = (f32x4){0.f,0.f,0.f,0.f}, s_z = (f32x4){0.f,0.f,0.f,0.f};
        f32x4 m_gin = (f32x4){0.f,0.f,0.f,0.f}, s_gin = (f32x4){0.f,0.f,0.f,0.f};
        f32x4 m_ghn = (f32x4){0.f,0.f,0.f,0.f}, s_ghn = (f32x4){0.f,0.f,0.f,0.f};

        // (C) gi = x_t @ W_ih^T, K-split: lower ks 0..3, upper ks 4..7
        const int cks0 = upper ? 4 : 0;
#pragma unroll
        for (int ksi = 0; ksi < 4; ++ksi) {
            const int k = (cks0 + ksi) * 32 + quad * 8;
            f16x8 Axh = *reinterpret_cast<const f16x8*>(&xl[rb][0][ln][k]);
            f16x8 Axl = *reinterpret_cast<const f16x8*>(&xl[rb][1][ln][k]);
#pragma unroll
            for (int g = 0; g < 3; ++g) {
                const ushortT* wr = wih2 + (size_t)(g * 512 + j_lane) * 256 + k;
                f16x8 Wh = *reinterpret_cast<const f16x8*>(wr);
                f16x8 Wl = *reinterpret_cast<const f16x8*>(wr + 393216);
                if (g == 0) {
                    m_r = MFMAH(Axh, Wh, m_r);
                    s_r = MFMAH(Axl, Wh, s_r);
                    s_r = MFMAH(Axh, Wl, s_r);
                } else if (g == 1) {
                    m_z = MFMAH(Axh, Wh, m_z);
                    s_z = MFMAH(Axl, Wh, s_z);
                    s_z = MFMAH(Axh, Wl, s_z);
                } else {
                    m_gin = MFMAH(Axh, Wh, m_gin);
                    s_gin = MFMAH(Axl, Wh, s_gin);
                    s_gin = MFMAH(Axh, Wl, s_gin);
                }
            }
        }

        // (D0) flag wait: threads 0..7 each spin on one producer flag
        if (tid < 8) {
            const unsigned want = (unsigned)t;
            unsigned* pp = flags + (unsigned)(cluster * 8 + tid) * 32u;
            unsigned f = __hip_atomic_load(pp, __ATOMIC_RELAXED,
                                           __HIP_MEMORY_SCOPE_AGENT);
            while (f < want) {
                __builtin_amdgcn_s_sleep(2);
                f = __hip_atomic_load(pp, __ATOMIC_RELAXED,
                                      __HIP_MEMORY_SCOPE_AGENT);
            }
        }
        __syncthreads();   // all 8 producer flags confirmed across the WG

        // (A) one bulk cooperative payload load: 16 atoms/thread, coalesced
        u64c v[16];
#pragma unroll
        for (int j = 0; j < 16; ++j)
            v[j] = __hip_atomic_load(tile + tid + 512 * j,
                                     __ATOMIC_RELAXED, __HIP_MEMORY_SCOPE_AGENT);

        // (D1) tag verify — safety net only; should pass first try
        const unsigned etag = (unsigned)t;
        for (;;) {
            bool ok = true;
#pragma unroll
            for (int j = 0; j < 16; ++j) ok &= ((unsigned)(v[j] >> 32) == etag);
            if (__all(ok)) break;
            __builtin_amdgcn_s_sleep(4);
#pragma unroll
            for (int j = 0; j < 16; ++j)
                v[j] = __hip_atomic_load(tile + tid + 512 * j,
                                         __ATOMIC_RELAXED, __HIP_MEMORY_SCOPE_AGENT);
        }

        // (E) publish packed payloads to LDS tile
#pragma unroll
        for (int j = 0; j < 16; ++j) {
            const int a = tid + 512 * j;
            hl[(a >> 9) * 516 + (a & 511)] = (unsigned)v[j];
        }
        __syncthreads();

        // (F) gh = h_{t-1} @ W_hh^T, K-split: lower ks 0..7, upper ks 8..15
        const int fks0 = upper ? 8 : 0;
#pragma unroll
        for (int ksi = 0; ksi < 8; ++ksi) {
            const int k = (fks0 + ksi) * 32 + quad * 8;
            const unsigned* hp = &hl[ln * 516 + k];
            u32x4 q0 = *reinterpret_cast<const u32x4*>(hp);
            u32x4 q1 = *reinterpret_cast<const u32x4*>(hp + 4);
            u32x4 ah, al;
#pragma unroll
            for (int i = 0; i < 2; ++i) {
                ah[i]   = (q0[2*i] & 0xffffu) | (q0[2*i+1] << 16);
                al[i]   = (q0[2*i] >> 16)     | (q0[2*i+1] & 0xffff0000u);
                ah[2+i] = (q1[2*i] & 0xffffu) | (q1[2*i+1] << 16);
                al[2+i] = (q1[2*i] >> 16)     | (q1[2*i+1] & 0xffff0000u);
            }
            f16x8 Ah = __builtin_bit_cast(f16x8, ah);
            f16x8 Al = __builtin_bit_cast(f16x8, al);
#pragma unroll
            for (int g = 0; g < 3; ++g) {
                const ushortT* wr = whh2 + (size_t)(g * 512 + j_lane) * 512 + k;
                f16x8 Wh = *reinterpret_cast<const f16x8*>(wr);
                f16x8 Wl = *reinterpret_cast<const f16x8*>(wr + 786432);
                if (g == 0) {
                    m_r = MFMAH(Ah, Wh, m_r);
                    s_r = MFMAH(Al, Wh, s_r);
                    s_r = MFMAH(Ah, Wl, s_r);
                } else if (g == 1) {
                    m_z = MFMAH(Ah, Wh, m_z);
                    s_z = MFMAH(Al, Wh, s_z);
                    s_z = MFMAH(Ah, Wl, s_z);
                } else {
                    m_ghn = MFMAH(Ah, Wh, m_ghn);
                    s_ghn = MFMAH(Al, Wh, s_ghn);
                    s_ghn = MFMAH(Ah, Wl, s_ghn);
                }
            }
        }

        // (R) upper waves dump partials to LDS (lane-consecutive 16B: conflict-free)
        if (upper) {
            const int u = wave - 4;
            pl[u][0][lane] = m_r;   pl[u][1][lane] = s_r;
            pl[u][2][lane] = m_z;   pl[u][3][lane] = s_z;
            pl[u][4][lane] = m_gin; pl[u][5][lane] = s_gin;
            pl[u][6][lane] = m_ghn; pl[u][7][lane] = s_ghn;
        }
        __syncthreads();

        float hn4[4];
        if (!upper) {
            // combine K-halves
            m_r   += pl[wave][0][lane]; s_r   += pl[wave][1][lane];
            m_z   += pl[wave][2][lane]; s_z   += pl[wave][3][lane];
            m_gin += pl[wave][4][lane]; s_gin += pl[wave][5][lane];
            m_ghn += pl[wave][6][lane]; s_ghn += pl[wave][7][lane];

            // (G) gates + h_new; tagged h stores (drained by the next barrier)
            u64c* hw = hbt + (size_t)wb * 32768;
            const u64c ntag = ((u64c)(unsigned)(t + 1)) << 32;
#pragma unroll
            for (int r4 = 0; r4 < 4; ++r4) {
                const float pre_r = m_r[r4] + s_r[r4] * KSC + c_r;
                const float pre_z = m_z[r4] + s_z[r4] * KSC + c_z;
                const float gin   = m_gin[r4] + s_gin[r4] * KSC + bi_n;
                const float ghn   = m_ghn[r4] + s_ghn[r4] * KSC + bh_n;
                const float rr = 1.f / (1.f + expf(-pre_r));
                const float zz = 1.f / (1.f + expf(-pre_z));
                const float nn = tanhf(gin + rr * ghn);
                const float hn = (1.f - zz) * nn + zz * hprev[r4];
                hprev[r4] = hn;
                hn4[r4] = hn;
                ushortT hi, lo; splitf(hn, hi, lo);
                const unsigned pk = (unsigned)hi | ((unsigned)lo << 16);
                const int b = m0 + quad * 4 + r4;
                __hip_atomic_store(&hw[b * 512 + j_lane], ntag | (u64c)pk,
                                   __ATOMIC_RELAXED, __HIP_MEMORY_SCOPE_AGENT);
            }
        } else {
            // (H) publish x_{t+1} into LDS buffer wb
#pragma unroll
            for (int i = 0; i < 16; ++i) {
                ushortT hi, lo; splitf(xv[i >> 2][i & 3], hi, lo);
                xl[wb][0][xr][xc + i] = hi; xl[wb][1][xr][xc + i] = lo;
            }
        }

        // barrier: each wave drains its own vmcnt before arriving -> all lower
        // waves' payload stores are at the coherence point; also xl/hl turnover
        __syncthreads();
        if (tid == 0)
            __hip_atomic_store(ownp, (unsigned)(t + 1),
                               __ATOMIC_RELAXED, __HIP_MEMORY_SCOPE_AGENT);

        // st stores — consumed only by k3 after this kernel; off critical path
        if (!upper) {
#pragma unroll
            for (int r4 = 0; r4 < 4; ++r4) {
                const int b = m0 + quad * 4 + r4;
                st[((size_t)b * 512 + t) * 512 + j_lane] = hn4[r4];
            }
        }
    }
}

// ---------- k3: tag logits + argmax + PAD mask (R5-identical) ----------
__global__ __launch_bounds__(256) void tag_argmax(
    const float* __restrict__ st, const ushortT* __restrict__ wtag2,
    const float* __restrict__ btag, const int* __restrict__ tok,
    float* __restrict__ out)
{
    const int wave = threadIdx.x >> 6;
    const int lane = threadIdx.x & 63;
    const int ln = lane & 15, quad = lane >> 4;
    const int mt = blockIdx.x * 4 + wave;   // 0..2047

    const float* arow = st + (size_t)(mt * 16 + ln) * 512;
    f32x4 am[4], as_[4];
#pragma unroll
    for (int ti = 0; ti < 4; ++ti) { am[ti] = (f32x4){0.f,0.f,0.f,0.f}; as_[ti] = (f32x4){0.f,0.f,0.f,0.f}; }

#pragma unroll
    for (int ks = 0; ks < 16; ++ks) {
        const int k = ks * 32 + quad * 8;
        f16x8 Ah, Al;
#pragma unroll
        for (int e = 0; e < 8; ++e) {
            const float x = arow[k + e];
            _Float16 h = (_Float16)x;
            Ah[e] = h;
            Al[e] = (_Float16)((x - (float)h) * 4096.0f);
        }
#pragma unroll
        for (int ti = 0; ti < 4; ++ti) {
            const ushortT* wr = wtag2 + (size_t)(ti * 16 + ln) * 512 + k;
            f16x8 Wh = *reinterpret_cast<const f16x8*>(wr);
            f16x8 Wl = *reinterpret_cast<const f16x8*>(wr + 32768);
            am[ti]  = MFMAH(Ah, Wh, am[ti]);
            as_[ti] = MFMAH(Ah, Wl, as_[ti]);
            as_[ti] = MFMAH(Al, Wh, as_[ti]);
        }
    }

    float vals[4][4];
#pragma unroll
    for (int ti = 0; ti < 4; ++ti) {
        const float bb = btag[ti * 16 + ln];
#pragma unroll
        for (int r = 0; r < 4; ++r) vals[ti][r] = am[ti][r] + as_[ti][r] * KSC + bb;
    }
#pragma unroll
    for (int ti = 0; ti < 4; ++ti)
#pragma unroll
        for (int r = 0; r < 4; ++r) {
            const int row = mt * 16 + quad * 4 + r;
            out[(size_t)row * 64 + ti * 16 + ln] = vals[ti][r];
        }
#pragma unroll
    for (int r = 0; r < 4; ++r) {
        float best = vals[0][r];
        int bc = ln;
#pragma unroll
        for (int ti = 1; ti < 4; ++ti) {
            const float v = vals[ti][r];
            const int c = ti * 16 + ln;
            if (v > best) { best = v; bc = c; }
        }
        for (int off = 1; off < 16; off <<= 1) {
            const float ov = __shfl_xor(best, off);
            const int oc = __shfl_xor(bc, off);
            if (ov > best || (ov == best && oc < bc)) { best = ov; bc = oc; }
        }
        if (ln == 0) {
            const int row = mt * 16 + quad * 4 + r;   // = b*512+t = token idx
            const int token = tok[row];
            const int pred = (token != 0) ? bc : 0;
            out[2097152 + (size_t)row] = (float)pred;
        }
    }
}

extern "C" void kernel_launch(void* const* d_in, const int* in_sizes, int n_in,
                              void* d_out, int out_size, void* d_ws, size_t ws_size,
                              hipStream_t stream) {
    const int*   tokens = (const int*)d_in[0];
    const float* emb    = (const float*)d_in[1];
    const float* Wih    = (const float*)d_in[2];
    const float* Whh    = (const float*)d_in[3];
    const float* bih    = (const float*)d_in[4];
    const float* bhh    = (const float*)d_in[5];
    const float* Wtag   = (const float*)d_in[6];
    const float* btag   = (const float*)d_in[7];

    char* ws = (char*)d_ws;
    u64c*     hbt   = (u64c*)ws;                     // 524,288 B
    ushortT*  whh2  = (ushortT*)(ws + 524288);       // 3,145,728 B
    ushortT*  wih2  = (ushortT*)(ws + 3670016);      // 1,572,864 B
    ushortT*  wtag2 = (ushortT*)(ws + 5242880);      // 131,072 B
    float*    stf   = (float*)(ws + 5373952);        // 67,108,864 B (total 72.48 MB)
    float*    out   = (float*)d_out;

    // Sync flags live in d_out's preds region (scratch during gru_rec;
    // tag_argmax rewrites every preds element afterwards). 32 flags, 128B pad.
    unsigned* flags = (unsigned*)(out + 2097152);

    split_weights<<<4736, 256, 0, stream>>>(Whh, Wih, Wtag, whh2, wih2, wtag2);
    init_ws<<<128, 256, 0, stream>>>((uint4*)ws, (uint4*)flags);
    gru_rec<<<32, 512, 0, stream>>>(tokens, emb, wih2, whh2, bih, bhh, hbt, stf, flags);
    tag_argmax<<<512, 256, 0, stream>>>(stf, wtag2, btag, tokens, out);
}

// Round 3
// 7237.379 us; speedup vs baseline: 1.2185x; 1.0103x over previous
//
#include <hip/hip_runtime.h>

// RnnTagger (f32 in / f32 out): tokens[64*512] i32; emb[50000,256]; W_ih[1536,256];
// W_hh[1536,512]; b_ih[1536]; b_hh[1536]; W_tag[64,512]; b_tag[64].
// d_out f32: tag_logits [64,512,64] then preds [64,512] flat.
//
// f32-faithful MFMA via f16 double-split: x ~= hi + lo/4096 (hi,lo f16); product
// = 3 f16 MFMAs (m += Ah*Wh; s += Al*Wh + Ah*Wl; result = m + s/4096).
//
// R9: attack the per-CU L2 W-stream (R8 streamed 590KB/WG/step ~ 4.4us at
// ~135GB/s per-CU L2 BW; step was 14.1us with only ~3.5us busy).
//  - W_hh HI-PLANE REGISTER-RESIDENT: each wave preloads its K-half x 16 cols
//    x 3 gates of the hi plane (24 x f16x8 = 96 VGPRs) before the t-loop.
//    Stream drops 590 -> 393 KB/WG/step. (W_ih-hi residency deferred: would
//    push VGPR ~240+, spill risk. Check VGPR_Count this round first.)
//  - h tile DE-PACKED AT PUBLISH: hi/lo stored as separate u16 LDS planes
//    (row stride 520 for bank spread); phase F reads A-frags with 2 direct
//    ds_read_b128 instead of 8 u32 reads + 16 bitops per ksi per wave.
// Structure otherwise identical to R8 (512-thr WGs, wave-pair K-split,
// tagged atoms + per-producer flags in d_out's preds region).
//
// ws (72,482,816 B, same layout as R5-R8):
//   [0,+524288)         h tagged dbuf  u64[2][64][512]
//   [524288,+3145728)   whh2  [hi/lo][1536][512] f16
//   [3670016,+1572864)  wih2  [hi/lo][1536][256] f16
//   [5242880,+131072)   wtag2 [hi/lo][64][512] f16
//   [5373952,+67108864) st    [b*512+t][512] f32

typedef unsigned short ushortT;
typedef unsigned long long u64c;
typedef float f32x4 __attribute__((ext_vector_type(4)));
typedef _Float16 f16x8 __attribute__((ext_vector_type(8)));
typedef unsigned int u32x4 __attribute__((ext_vector_type(4)));

#define MFMAH(a, b, c) __builtin_amdgcn_mfma_f32_16x16x32_f16((a), (b), (c), 0, 0, 0)
#define KSC (1.0f / 4096.0f)

__device__ __forceinline__ void splitf(float x, ushortT& hi, ushortT& lo) {
    _Float16 h = (_Float16)x;
    float r = x - (float)h;
    _Float16 l = (_Float16)(r * 4096.0f);
    hi = __builtin_bit_cast(ushortT, h);
    lo = __builtin_bit_cast(ushortT, l);
}

// ---------- k0: split weights into f16 hi/lo planes ----------
__global__ __launch_bounds__(256) void split_weights(
    const float* __restrict__ Whh, const float* __restrict__ Wih,
    const float* __restrict__ Wtag, ushortT* __restrict__ wh2,
    ushortT* __restrict__ wi2, ushortT* __restrict__ wt2)
{
    const int i = blockIdx.x * 256 + threadIdx.x;
    ushortT hi, lo;
    if (i < 786432) {                       // 1536*512
        splitf(Whh[i], hi, lo);
        wh2[i] = hi; wh2[786432 + i] = lo;
    } else if (i < 786432 + 393216) {       // 1536*256
        const int j = i - 786432;
        splitf(Wih[j], hi, lo);
        wi2[j] = hi; wi2[393216 + j] = lo;
    } else if (i < 786432 + 393216 + 32768) {   // 64*512
        const int j = i - 786432 - 393216;
        splitf(Wtag[j], hi, lo);
        wt2[j] = hi; wt2[32768 + j] = lo;
    }
}

// ---------- k1: zero tagged h double buffer (tag 0 = "after step -1") + flags ----------
__global__ void init_ws(uint4* p, uint4* f) {
    int i = blockIdx.x * blockDim.x + threadIdx.x;
    uint4 z; z.x = 0u; z.y = 0u; z.z = 0u; z.w = 0u;
    if (i < 32768) p[i] = z;    // 524288 B / 16
    if (i < 256)   f[i] = z;    // 4096 B of flags
}

// ---------- k2: fused gi + serial GRU recurrence ----------
// 32 WGs x 512 (8 waves = 2 waves/SIMD). cluster = bid>>3 owns batch rows
// [cluster*16,+16); jg = bid&7 owns h-cols [jg*64,+64). Wave pair (w, w+4)
// owns cols jg*64 + w*16 + [0,16), K-split across the pair.
__global__ __launch_bounds__(512, 1) void gru_rec(
    const int* __restrict__ tok, const float* __restrict__ emb,
    const ushortT* __restrict__ wih2, const ushortT* __restrict__ whh2,
    const float* __restrict__ bih, const float* __restrict__ bhh,
    u64c* __restrict__ hbt, float* __restrict__ st,
    unsigned* __restrict__ flags)
{
    __shared__ ushortT xl[2][2][16][264];   // 33792 B: x dbuf [buf][hi/lo][16 b][256k pad]
    __shared__ ushortT hlh[16 * 520];       // 16640 B: h hi plane [16 rows][512 + pad 8]
    __shared__ ushortT hll[16 * 520];       // 16640 B: h lo plane
    __shared__ f32x4 pl[4][8][64];          // 32768 B: upper-wave partials [u][vec][lane]

    const int bid = blockIdx.x;
    const int cluster = bid >> 3;
    const int jg = bid & 7;
    const int tid = threadIdx.x;
    const int wave = tid >> 6;
    const int lane = tid & 63;
    const int wl = wave & 3;                // pair column-slot 0..3
    const bool upper = wave >= 4;
    const int ln = lane & 15, quad = lane >> 4;
    const int m0 = cluster * 16;
    const int j_lane = jg * 64 + wl * 16 + ln;

    // 128B-padded flags: flags[(cluster*8 + jg)*32]; threads 0..7 poll.
    unsigned* ownp = flags + (unsigned)(cluster * 8 + jg) * 32u;

    const float c_r  = bih[j_lane]        + bhh[j_lane];
    const float c_z  = bih[512 + j_lane]  + bhh[512 + j_lane];
    const float bi_n = bih[1024 + j_lane];
    const float bh_n = bhh[1024 + j_lane];

    // K-range base for this wave's half of the gh reduction (also used to
    // select which hi-plane W_hh fragment block is register-resident).
    const int fks0 = upper ? 8 : 0;
    const int cks0 = upper ? 4 : 0;

    // W_hh hi-plane register-resident: 24 x f16x8 = 96 VGPRs/lane, loaded once.
    f16x8 whhHi[24];
#pragma unroll
    for (int ksi = 0; ksi < 8; ++ksi) {
        const int k = (fks0 + ksi) * 32 + quad * 8;
#pragma unroll
        for (int g = 0; g < 3; ++g)
            whhHi[ksi * 3 + g] = *reinterpret_cast<const f16x8*>(
                whh2 + (size_t)(g * 512 + j_lane) * 512 + k);
    }
    const ushortT* wlo = whh2 + 786432;     // W_hh lo plane (streamed from L2)

    // Prologue: upper 256 threads stage x_0 into LDS buf 0.
    const int xr = (tid & 255) >> 4, xc = (tid & 15) * 16;
    if (upper) {
        const int token = tok[(m0 + xr) * 512];
        const float* xsrc = emb + (size_t)token * 256 + xc;
#pragma unroll
        for (int i = 0; i < 16; ++i) {
            ushortT hi, lo; splitf(xsrc[i], hi, lo);
            xl[0][0][xr][xc + i] = hi; xl[0][1][xr][xc + i] = lo;
        }
    }
    __syncthreads();

    float hprev[4] = {0.f, 0.f, 0.f, 0.f};

    for (int t = 0; t < 512; ++t) {
        const int rb = t & 1;
        const int wb = rb ^ 1;
        u64c* tile = hbt + (size_t)rb * 32768 + (size_t)m0 * 512;

        // (B) upper: x_{t+1} global loads into regs (published in phase H)
        f32x4 xv[4];
        if (upper) {
            const int tp = (t + 1) & 511;
            const int xtoken = tok[(m0 + xr) * 512 + tp];
            const float* xsrc = emb + (size_t)xtoken * 256 + xc;
#pragma unroll
            for (int i = 0; i < 4; ++i)
                xv[i] = *reinterpret_cast<const f32x4*>(xsrc + i * 4);
        }

        // per-pair partial accumulators
        f32x4 m_r = (f32x4){0.f,0.f,0.f,0.f}, s_r = (f32x4){0.f,0.f,0.f,0.f};
        f32x4 m_z = (f32x4){0.f,0.f,0.f,0.f}, s_z = (f32x4){0.f,0.f,0.f,0.f};
        f32x4 m_gin = (f32x4){0.f,0.f,0.f,0.f}, s_gin = (f32x4){0.f,0.f,0.f,0.f};
        f32x4 m_ghn = (f32x4){0.f,0.f,0.f,0.f}, s_ghn = (f32x4){0.f,0.f,0.f,0.f};

        // (C) gi = x_t @ W_ih^T, K-split: lower ks 0..3, upper ks 4..7
#pragma unroll
        for (int ksi = 0; ksi < 4; ++ksi) {
            const int k = (cks0 + ksi) * 32 + quad * 8;
            f16x8 Axh = *reinterpret_cast<const f16x8*>(&xl[rb][0][ln][k]);
            f16x8 Axl = *reinterpret_cast<const f16x8*>(&xl[rb][1][ln][k]);
#pragma unroll
            for (int g = 0; g < 3; ++g) {
                const ushortT* wr = wih2 + (size_t)(g * 512 + j_lane) * 256 + k;
                f16x8 Wh = *reinterpret_cast<const f16x8*>(wr);
                f16x8 Wl = *reinterpret_cast<const f16x8*>(wr + 393216);
                if (g == 0) {
                    m_r = MFMAH(Axh, Wh, m_r);
                    s_r = MFMAH(Axl, Wh, s_r);
                    s_r = MFMAH(Axh, Wl, s_r);
                } else if (g == 1) {
                    m_z = MFMAH(Axh, Wh, m_z);
                    s_z = MFMAH(Axl, Wh, s_z);
                    s_z = MFMAH(Axh, Wl, s_z);
                } else {
                    m_gin = MFMAH(Axh, Wh, m_gin);
                    s_gin = MFMAH(Axl, Wh, s_gin);
                    s_gin = MFMAH(Axh, Wl, s_gin);
                }
            }
        }

        // (D0) flag wait: threads 0..7 each spin on one producer flag
        if (tid < 8) {
            const unsigned want = (unsigned)t;
            unsigned* pp = flags + (unsigned)(cluster * 8 + tid) * 32u;
            unsigned f = __hip_atomic_load(pp, __ATOMIC_RELAXED,
                                           __HIP_MEMORY_SCOPE_AGENT);
            while (f < want) {
                __builtin_amdgcn_s_sleep(2);
                f = __hip_atomic_load(pp, __ATOMIC_RELAXED,
                                      __HIP_MEMORY_SCOPE_AGENT);
            }
        }
        __syncthreads();   // all 8 producer flags confirmed across the WG

        // (A) one bulk cooperative payload load: 16 atoms/thread, coalesced
        u64c v[16];
#pragma unroll
        for (int j = 0; j < 16; ++j)
            v[j] = __hip_atomic_load(tile + tid + 512 * j,
                                     __ATOMIC_RELAXED, __HIP_MEMORY_SCOPE_AGENT);

        // (D1) tag verify — safety net only; should pass first try
        const unsigned etag = (unsigned)t;
        for (;;) {
            bool ok = true;
#pragma unroll
            for (int j = 0; j < 16; ++j) ok &= ((unsigned)(v[j] >> 32) == etag);
            if (__all(ok)) break;
            __builtin_amdgcn_s_sleep(4);
#pragma unroll
            for (int j = 0; j < 16; ++j)
                v[j] = __hip_atomic_load(tile + tid + 512 * j,
                                         __ATOMIC_RELAXED, __HIP_MEMORY_SCOPE_AGENT);
        }

        // (E) publish DE-PACKED hi/lo planes to LDS (row = j, col = tid)
#pragma unroll
        for (int j = 0; j < 16; ++j) {
            const unsigned pk = (unsigned)v[j];
            hlh[j * 520 + tid] = (ushortT)(pk & 0xffffu);
            hll[j * 520 + tid] = (ushortT)(pk >> 16);
        }
        __syncthreads();

        // (F) gh = h_{t-1} @ W_hh^T, K-split: lower ks 0..7, upper ks 8..15.
        // A-frags: direct b128 from de-packed planes. Wh: registers. Wl: L2.
#pragma unroll
        for (int ksi = 0; ksi < 8; ++ksi) {
            const int k = (fks0 + ksi) * 32 + quad * 8;
            f16x8 Ah = *reinterpret_cast<const f16x8*>(&hlh[ln * 520 + k]);
            f16x8 Al = *reinterpret_cast<const f16x8*>(&hll[ln * 520 + k]);
#pragma unroll
            for (int g = 0; g < 3; ++g) {
                f16x8 Wh = whhHi[ksi * 3 + g];
                f16x8 Wl = *reinterpret_cast<const f16x8*>(
                    wlo + (size_t)(g * 512 + j_lane) * 512 + k);
                if (g == 0) {
                    m_r = MFMAH(Ah, Wh, m_r);
                    s_r = MFMAH(Al, Wh, s_r);
                    s_r = MFMAH(Ah, Wl, s_r);
                } else if (g == 1) {
                    m_z = MFMAH(Ah, Wh, m_z);
                    s_z = MFMAH(Al, Wh, s_z);
                    s_z = MFMAH(Ah, Wl, s_z);
                } else {
                    m_ghn = MFMAH(Ah, Wh, m_ghn);
                    s_ghn = MFMAH(Al, Wh, s_ghn);
                    s_ghn = MFMAH(Ah, Wl, s_ghn);
                }
            }
        }

        // (R) upper waves dump partials to LDS (lane-consecutive 16B: conflict-free)
        if (upper) {
            const int u = wave - 4;
            pl[u][0][lane] = m_r;   pl[u][1][lane] = s_r;
            pl[u][2][lane] = m_z;   pl[u][3][lane] = s_z;
            pl[u][4][lane] = m_gin; pl[u][5][lane] = s_gin;
            pl[u][6][lane] = m_ghn; pl[u][7][lane] = s_ghn;
        }
        __syncthreads();

        float hn4[4];
        if (!upper) {
            // combine K-halves
            m_r   += pl[wave][0][lane]; s_r   += pl[wave][1][lane];
            m_z   += pl[wave][2][lane]; s_z   += pl[wave][3][lane];
            m_gin += pl[wave][4][lane]; s_gin += pl[wave][5][lane];
            m_ghn += pl[wave][6][lane]; s_ghn += pl[wave][7][lane];

            // (G) gates + h_new; tagged h stores (drained by the next barrier)
            u64c* hw = hbt + (size_t)wb * 32768;
            const u64c ntag = ((u64c)(unsigned)(t + 1)) << 32;
#pragma unroll
            for (int r4 = 0; r4 < 4; ++r4) {
                const float pre_r = m_r[r4] + s_r[r4] * KSC + c_r;
                const float pre_z = m_z[r4] + s_z[r4] * KSC + c_z;
                const float gin   = m_gin[r4] + s_gin[r4] * KSC + bi_n;
                const float ghn   = m_ghn[r4] + s_ghn[r4] * KSC + bh_n;
                const float rr = 1.f / (1.f + expf(-pre_r));
                const float zz = 1.f / (1.f + expf(-pre_z));
                const float nn = tanhf(gin + rr * ghn);
                const float hn = (1.f - zz) * nn + zz * hprev[r4];
                hprev[r4] = hn;
                hn4[r4] = hn;
                ushortT hi, lo; splitf(hn, hi, lo);
                const unsigned pk = (unsigned)hi | ((unsigned)lo << 16);
                const int b = m0 + quad * 4 + r4;
                __hip_atomic_store(&hw[b * 512 + j_lane], ntag | (u64c)pk,
                                   __ATOMIC_RELAXED, __HIP_MEMORY_SCOPE_AGENT);
            }
        } else {
            // (H) publish x_{t+1} into LDS buffer wb
#pragma unroll
            for (int i = 0; i < 16; ++i) {
                ushortT hi, lo; splitf(xv[i >> 2][i & 3], hi, lo);
                xl[wb][0][xr][xc + i] = hi; xl[wb][1][xr][xc + i] = lo;
            }
        }

        // barrier: each wave drains its own vmcnt before arriving -> all lower
        // waves' payload stores are at the coherence point; also xl/hl turnover
        __syncthreads();
        if (tid == 0)
            __hip_atomic_store(ownp, (unsigned)(t + 1),
                               __ATOMIC_RELAXED, __HIP_MEMORY_SCOPE_AGENT);

        // st stores — consumed only by k3 after this kernel; off critical path
        if (!upper) {
#pragma unroll
            for (int r4 = 0; r4 < 4; ++r4) {
                const int b = m0 + quad * 4 + r4;
                st[((size_t)b * 512 + t) * 512 + j_lane] = hn4[r4];
            }
        }
    }
}

// ---------- k3: tag logits + argmax + PAD mask (R5-identical) ----------
__global__ __launch_bounds__(256) void tag_argmax(
    const float* __restrict__ st, const ushortT* __restrict__ wtag2,
    const float* __restrict__ btag, const int* __restrict__ tok,
    float* __restrict__ out)
{
    const int wave = threadIdx.x >> 6;
    const int lane = threadIdx.x & 63;
    const int ln = lane & 15, quad = lane >> 4;
    const int mt = blockIdx.x * 4 + wave;   // 0..2047

    const float* arow = st + (size_t)(mt * 16 + ln) * 512;
    f32x4 am[4], as_[4];
#pragma unroll
    for (int ti = 0; ti < 4; ++ti) { am[ti] = (f32x4){0.f,0.f,0.f,0.f}; as_[ti] = (f32x4){0.f,0.f,0.f,0.f}; }

#pragma unroll
    for (int ks = 0; ks < 16; ++ks) {
        const int k = ks * 32 + quad * 8;
        f16x8 Ah, Al;
#pragma unroll
        for (int e = 0; e < 8; ++e) {
            const float x = arow[k + e];
            _Float16 h = (_Float16)x;
            Ah[e] = h;
            Al[e] = (_Float16)((x - (float)h) * 4096.0f);
        }
#pragma unroll
        for (int ti = 0; ti < 4; ++ti) {
            const ushortT* wr = wtag2 + (size_t)(ti * 16 + ln) * 512 + k;
            f16x8 Wh = *reinterpret_cast<const f16x8*>(wr);
            f16x8 Wl = *reinterpret_cast<const f16x8*>(wr + 32768);
            am[ti]  = MFMAH(Ah, Wh, am[ti]);
            as_[ti] = MFMAH(Ah, Wl, as_[ti]);
            as_[ti] = MFMAH(Al, Wh, as_[ti]);
        }
    }

    float vals[4][4];
#pragma unroll
    for (int ti = 0; ti < 4; ++ti) {
        const float bb = btag[ti * 16 + ln];
#pragma unroll
        for (int r = 0; r < 4; ++r) vals[ti][r] = am[ti][r] + as_[ti][r] * KSC + bb;
    }
#pragma unroll
    for (int ti = 0; ti < 4; ++ti)
#pragma unroll
        for (int r = 0; r < 4; ++r) {
            const int row = mt * 16 + quad * 4 + r;
            out[(size_t)row * 64 + ti * 16 + ln] = vals[ti][r];
        }
#pragma unroll
    for (int r = 0; r < 4; ++r) {
        float best = vals[0][r];
        int bc = ln;
#pragma unroll
        for (int ti = 1; ti < 4; ++ti) {
            const float v = vals[ti][r];
            const int c = ti * 16 + ln;
            if (v > best) { best = v; bc = c; }
        }
        for (int off = 1; off < 16; off <<= 1) {
            const float ov = __shfl_xor(best, off);
            const int oc = __shfl_xor(bc, off);
            if (ov > best || (ov == best && oc < bc)) { best = ov; bc = oc; }
        }
        if (ln == 0) {
            const int row = mt * 16 + quad * 4 + r;   // = b*512+t = token idx
            const int token = tok[row];
            const int pred = (token != 0) ? bc : 0;
            out[2097152 + (size_t)row] = (float)pred;
        }
    }
}

extern "C" void kernel_launch(void* const* d_in, const int* in_sizes, int n_in,
                              void* d_out, int out_size, void* d_ws, size_t ws_size,
                              hipStream_t stream) {
    const int*   tokens = (const int*)d_in[0];
    const float* emb    = (const float*)d_in[1];
    const float* Wih    = (const float*)d_in[2];
    const float* Whh    = (const float*)d_in[3];
    const float* bih    = (const float*)d_in[4];
    const float* bhh    = (const float*)d_in[5];
    const float* Wtag   = (const float*)d_in[6];
    const float* btag   = (const float*)d_in[7];

    char* ws = (char*)d_ws;
    u64c*     hbt   = (u64c*)ws;                     // 524,288 B
    ushortT*  whh2  = (ushortT*)(ws + 524288);       // 3,145,728 B
    ushortT*  wih2  = (ushortT*)(ws + 3670016);      // 1,572,864 B
    ushortT*  wtag2 = (ushortT*)(ws + 5242880);      // 131,072 B
    float*    stf   = (float*)(ws + 5373952);        // 67,108,864 B (total 72.48 MB)
    float*    out   = (float*)d_out;

    // Sync flags live in d_out's preds region (scratch during gru_rec;
    // tag_argmax rewrites every preds element afterwards). 32 flags, 128B pad.
    unsigned* flags = (unsigned*)(out + 2097152);

    split_weights<<<4736, 256, 0, stream>>>(Whh, Wih, Wtag, whh2, wih2, wtag2);
    init_ws<<<128, 256, 0, stream>>>((uint4*)ws, (uint4*)flags);
    gru_rec<<<32, 512, 0, stream>>>(tokens, emb, wih2, whh2, bih, bhh, hbt, stf, flags);
    tag_argmax<<<512, 256, 0, stream>>>(stf, wtag2, btag, tokens, out);
}

// Round 5
// 6481.302 us; speedup vs baseline: 1.3606x; 1.1167x over previous
//
#include <hip/hip_runtime.h>

// RnnTagger (f32 in / f32 out): tokens[64*512] i32; emb[50000,256]; W_ih[1536,256];
// W_hh[1536,512]; b_ih[1536]; b_hh[1536]; W_tag[64,512]; b_tag[64].
// d_out f32: tag_logits [64,512,64] then preds [64,512] flat.
//
// f32-faithful MFMA via f16 double-split: x ~= hi + lo/4096 (hi,lo f16); product
// = 3 f16 MFMAs (m += Ah*Wh; s += Al*Wh + Ah*Wl; result = m + s/4096).
//
// R11 = R10's traffic shrink, compiler-safe. R10 failed NaN: inline-asm
// global_load_dwordx4 + separate s_waitcnt asm -> hipcc hoisted the register-
// only de-pack past the waitcnt (guide rule: "memory" clobber doesn't order
// register-only ops) -> undefined registers. R11 keeps the same exchange
// shrink but reads payload with __hip_atomic_load on u64 (known-good sc
// codegen, zero asm):
//  - TAGS DROPPED: flag-only sync (R7-R9's tag-verify never fired; producer
//    stores -> __syncthreads drains vmcnt -> flag store => payload visible).
//    Payload element: 4B pk. Exchange buffer 512 -> 256 KB.
//  - u64 ATOMIC READS carry TWO pk's each: 4096 transactions/tile vs R9's
//    8192, 32KB vs 64KB bytes. De-pack 2 cols/atom into hi/lo LDS planes
//    with packed u32 writes.
//  - h stores 4B atomics (half of R9's write bytes). Tag-verify deleted.
// Structure otherwise = R9 (512-thr WGs, wave-pair K-split, de-packed LDS
// h planes, per-producer flags in d_out's preds region).
//
// ws (72,482,816 B; hbt shrank, other offsets kept):
//   [0,+262144)         h pk dbuf  u32[2][64][512]
//   [524288,+3145728)   whh2  [hi/lo][1536][512] f16
//   [3670016,+1572864)  wih2  [hi/lo][1536][256] f16
//   [5242880,+131072)   wtag2 [hi/lo][64][512] f16
//   [5373952,+67108864) st    [b*512+t][512] f32

typedef unsigned short ushortT;
typedef unsigned long long u64c;
typedef float f32x4 __attribute__((ext_vector_type(4)));
typedef _Float16 f16x8 __attribute__((ext_vector_type(8)));
typedef unsigned int u32x4 __attribute__((ext_vector_type(4)));

#define MFMAH(a, b, c) __builtin_amdgcn_mfma_f32_16x16x32_f16((a), (b), (c), 0, 0, 0)
#define KSC (1.0f / 4096.0f)

__device__ __forceinline__ void splitf(float x, ushortT& hi, ushortT& lo) {
    _Float16 h = (_Float16)x;
    float r = x - (float)h;
    _Float16 l = (_Float16)(r * 4096.0f);
    hi = __builtin_bit_cast(ushortT, h);
    lo = __builtin_bit_cast(ushortT, l);
}

// ---------- k0: split weights into f16 hi/lo planes ----------
__global__ __launch_bounds__(256) void split_weights(
    const float* __restrict__ Whh, const float* __restrict__ Wih,
    const float* __restrict__ Wtag, ushortT* __restrict__ wh2,
    ushortT* __restrict__ wi2, ushortT* __restrict__ wt2)
{
    const int i = blockIdx.x * 256 + threadIdx.x;
    ushortT hi, lo;
    if (i < 786432) {                       // 1536*512
        splitf(Whh[i], hi, lo);
        wh2[i] = hi; wh2[786432 + i] = lo;
    } else if (i < 786432 + 393216) {       // 1536*256
        const int j = i - 786432;
        splitf(Wih[j], hi, lo);
        wi2[j] = hi; wi2[393216 + j] = lo;
    } else if (i < 786432 + 393216 + 32768) {   // 64*512
        const int j = i - 786432 - 393216;
        splitf(Wtag[j], hi, lo);
        wt2[j] = hi; wt2[32768 + j] = lo;
    }
}

// ---------- k1: zero h pk double buffer + flags ----------
__global__ void init_ws(uint4* p, uint4* f) {
    int i = blockIdx.x * blockDim.x + threadIdx.x;
    uint4 z; z.x = 0u; z.y = 0u; z.z = 0u; z.w = 0u;
    if (i < 16384) p[i] = z;    // 262144 B / 16
    if (i < 256)   f[i] = z;    // 4096 B of flags
}

// ---------- k2: fused gi + serial GRU recurrence ----------
// 32 WGs x 512 (8 waves = 2 waves/SIMD). cluster = bid>>3 owns batch rows
// [cluster*16,+16); jg = bid&7 owns h-cols [jg*64,+64). Wave pair (w, w+4)
// owns cols jg*64 + w*16 + [0,16), K-split across the pair.
__global__ __launch_bounds__(512, 1) void gru_rec(
    const int* __restrict__ tok, const float* __restrict__ emb,
    const ushortT* __restrict__ wih2, const ushortT* __restrict__ whh2,
    const float* __restrict__ bih, const float* __restrict__ bhh,
    unsigned* __restrict__ hb32, float* __restrict__ st,
    unsigned* __restrict__ flags)
{
    __shared__ ushortT xl[2][2][16][264];   // 33792 B: x dbuf [buf][hi/lo][16 b][256k pad]
    __shared__ ushortT hlh[16 * 520];       // 16640 B: h hi plane [16 rows][512 + pad 8]
    __shared__ ushortT hll[16 * 520];       // 16640 B: h lo plane
    __shared__ f32x4 pl[4][8][64];          // 32768 B: upper-wave partials [u][vec][lane]

    const int bid = blockIdx.x;
    const int cluster = bid >> 3;
    const int jg = bid & 7;
    const int tid = threadIdx.x;
    const int wave = tid >> 6;
    const int lane = tid & 63;
    const int wl = wave & 3;                // pair column-slot 0..3
    const bool upper = wave >= 4;
    const int ln = lane & 15, quad = lane >> 4;
    const int m0 = cluster * 16;
    const int j_lane = jg * 64 + wl * 16 + ln;

    // 128B-padded flags: flags[(cluster*8 + jg)*32]; threads 0..7 poll.
    unsigned* ownp = flags + (unsigned)(cluster * 8 + jg) * 32u;

    const float c_r  = bih[j_lane]        + bhh[j_lane];
    const float c_z  = bih[512 + j_lane]  + bhh[512 + j_lane];
    const float bi_n = bih[1024 + j_lane];
    const float bh_n = bhh[1024 + j_lane];

    const int fks0 = upper ? 8 : 0;
    const int cks0 = upper ? 4 : 0;

    // Prologue: upper 256 threads stage x_0 into LDS buf 0.
    const int xr = (tid & 255) >> 4, xc = (tid & 15) * 16;
    if (upper) {
        const int token = tok[(m0 + xr) * 512];
        const float* xsrc = emb + (size_t)token * 256 + xc;
#pragma unroll
        for (int i = 0; i < 16; ++i) {
            ushortT hi, lo; splitf(xsrc[i], hi, lo);
            xl[0][0][xr][xc + i] = hi; xl[0][1][xr][xc + i] = lo;
        }
    }
    __syncthreads();

    float hprev[4] = {0.f, 0.f, 0.f, 0.f};

    for (int t = 0; t < 512; ++t) {
        const int rb = t & 1;
        const int wb = rb ^ 1;
        const u64c* tile64 =
            (const u64c*)(hb32 + (size_t)rb * 32768 + (size_t)m0 * 512);

        // (B) upper: x_{t+1} global loads into regs (published in phase H)
        f32x4 xv[4];
        if (upper) {
            const int tp = (t + 1) & 511;
            const int xtoken = tok[(m0 + xr) * 512 + tp];
            const float* xsrc = emb + (size_t)xtoken * 256 + xc;
#pragma unroll
            for (int i = 0; i < 4; ++i)
                xv[i] = *reinterpret_cast<const f32x4*>(xsrc + i * 4);
        }

        // per-pair partial accumulators
        f32x4 m_r = (f32x4){0.f,0.f,0.f,0.f}, s_r = (f32x4){0.f,0.f,0.f,0.f};
        f32x4 m_z = (f32x4){0.f,0.f,0.f,0.f}, s_z = (f32x4){0.f,0.f,0.f,0.f};
        f32x4 m_gin = (f32x4){0.f,0.f,0.f,0.f}, s_gin = (f32x4){0.f,0.f,0.f,0.f};
        f32x4 m_ghn = (f32x4){0.f,0.f,0.f,0.f}, s_ghn = (f32x4){0.f,0.f,0.f,0.f};

        // (C) gi = x_t @ W_ih^T, K-split: lower ks 0..3, upper ks 4..7
#pragma unroll
        for (int ksi = 0; ksi < 4; ++ksi) {
            const int k = (cks0 + ksi) * 32 + quad * 8;
            f16x8 Axh = *reinterpret_cast<const f16x8*>(&xl[rb][0][ln][k]);
            f16x8 Axl = *reinterpret_cast<const f16x8*>(&xl[rb][1][ln][k]);
#pragma unroll
            for (int g = 0; g < 3; ++g) {
                const ushortT* wr = wih2 + (size_t)(g * 512 + j_lane) * 256 + k;
                f16x8 Wh = *reinterpret_cast<const f16x8*>(wr);
                f16x8 Wl = *reinterpret_cast<const f16x8*>(wr + 393216);
                if (g == 0) {
                    m_r = MFMAH(Axh, Wh, m_r);
                    s_r = MFMAH(Axl, Wh, s_r);
                    s_r = MFMAH(Axh, Wl, s_r);
                } else if (g == 1) {
                    m_z = MFMAH(Axh, Wh, m_z);
                    s_z = MFMAH(Axl, Wh, s_z);
                    s_z = MFMAH(Axh, Wl, s_z);
                } else {
                    m_gin = MFMAH(Axh, Wh, m_gin);
                    s_gin = MFMAH(Axl, Wh, s_gin);
                    s_gin = MFMAH(Axh, Wl, s_gin);
                }
            }
        }

        // (D0) flag wait: threads 0..7 each spin on one producer flag
        if (tid < 8) {
            const unsigned want = (unsigned)t;
            unsigned* pp = flags + (unsigned)(cluster * 8 + tid) * 32u;
            unsigned f = __hip_atomic_load(pp, __ATOMIC_RELAXED,
                                           __HIP_MEMORY_SCOPE_AGENT);
            while (f < want) {
                __builtin_amdgcn_s_sleep(2);
                f = __hip_atomic_load(pp, __ATOMIC_RELAXED,
                                      __HIP_MEMORY_SCOPE_AGENT);
            }
        }
        __syncthreads();   // all 8 producer flags confirmed across the WG

        // (A) payload read: 8 u64 agent-coherent atomic loads per thread,
        // each carrying TWO 4B pk's. Flag-sync guarantees visibility.
        u64c v[8];
#pragma unroll
        for (int j = 0; j < 8; ++j)
            v[j] = __hip_atomic_load(tile64 + tid + 512 * j,
                                     __ATOMIC_RELAXED, __HIP_MEMORY_SCOPE_AGENT);

        // (E) publish DE-PACKED hi/lo planes to LDS: 2 cols per atom,
        // packed u32 writes (4B-aligned since c2 and row stride are even)
#pragma unroll
        for (int j = 0; j < 8; ++j) {
            const int a = tid + 512 * j;        // u64 index in [0,4096)
            const int row = a >> 8;             // 0..15
            const int c2 = (a & 255) * 2;       // 0,2,...,510
            const unsigned lo32 = (unsigned)v[j];
            const unsigned hi32 = (unsigned)(v[j] >> 32);
            *reinterpret_cast<unsigned*>(&hlh[row * 520 + c2]) =
                (lo32 & 0xffffu) | (hi32 << 16);
            *reinterpret_cast<unsigned*>(&hll[row * 520 + c2]) =
                (lo32 >> 16) | (hi32 & 0xffff0000u);
        }
        __syncthreads();

        // (F) gh = h_{t-1} @ W_hh^T, K-split: lower ks 0..7, upper ks 8..15.
        // A-frags: direct b128 from de-packed planes. W: streamed from L2.
#pragma unroll
        for (int ksi = 0; ksi < 8; ++ksi) {
            const int k = (fks0 + ksi) * 32 + quad * 8;
            f16x8 Ah = *reinterpret_cast<const f16x8*>(&hlh[ln * 520 + k]);
            f16x8 Al = *reinterpret_cast<const f16x8*>(&hll[ln * 520 + k]);
#pragma unroll
            for (int g = 0; g < 3; ++g) {
                const ushortT* wr = whh2 + (size_t)(g * 512 + j_lane) * 512 + k;
                f16x8 Wh = *reinterpret_cast<const f16x8*>(wr);
                f16x8 Wl = *reinterpret_cast<const f16x8*>(wr + 786432);
                if (g == 0) {
                    m_r = MFMAH(Ah, Wh, m_r);
                    s_r = MFMAH(Al, Wh, s_r);
                    s_r = MFMAH(Ah, Wl, s_r);
                } else if (g == 1) {
                    m_z = MFMAH(Ah, Wh, m_z);
                    s_z = MFMAH(Al, Wh, s_z);
                    s_z = MFMAH(Ah, Wl, s_z);
                } else {
                    m_ghn = MFMAH(Ah, Wh, m_ghn);
                    s_ghn = MFMAH(Al, Wh, s_ghn);
                    s_ghn = MFMAH(Ah, Wl, s_ghn);
                }
            }
        }

        // (R) upper waves dump partials to LDS (lane-consecutive 16B: conflict-free)
        if (upper) {
            const int u = wave - 4;
            pl[u][0][lane] = m_r;   pl[u][1][lane] = s_r;
            pl[u][2][lane] = m_z;   pl[u][3][lane] = s_z;
            pl[u][4][lane] = m_gin; pl[u][5][lane] = s_gin;
            pl[u][6][lane] = m_ghn; pl[u][7][lane] = s_ghn;
        }
        __syncthreads();

        float hn4[4];
        if (!upper) {
            // combine K-halves
            m_r   += pl[wave][0][lane]; s_r   += pl[wave][1][lane];
            m_z   += pl[wave][2][lane]; s_z   += pl[wave][3][lane];
            m_gin += pl[wave][4][lane]; s_gin += pl[wave][5][lane];
            m_ghn += pl[wave][6][lane]; s_ghn += pl[wave][7][lane];

            // (G) gates + h_new; 4B pk stores (drained by the next barrier)
            unsigned* hw32 = hb32 + (size_t)wb * 32768;
#pragma unroll
            for (int r4 = 0; r4 < 4; ++r4) {
                const float pre_r = m_r[r4] + s_r[r4] * KSC + c_r;
                const float pre_z = m_z[r4] + s_z[r4] * KSC + c_z;
                const float gin   = m_gin[r4] + s_gin[r4] * KSC + bi_n;
                const float ghn   = m_ghn[r4] + s_ghn[r4] * KSC + bh_n;
                const float rr = 1.f / (1.f + expf(-pre_r));
                const float zz = 1.f / (1.f + expf(-pre_z));
                const float nn = tanhf(gin + rr * ghn);
                const float hn = (1.f - zz) * nn + zz * hprev[r4];
                hprev[r4] = hn;
                hn4[r4] = hn;
                ushortT hi, lo; splitf(hn, hi, lo);
                const unsigned pk = (unsigned)hi | ((unsigned)lo << 16);
                const int b = m0 + quad * 4 + r4;
                __hip_atomic_store(&hw32[b * 512 + j_lane], pk,
                                   __ATOMIC_RELAXED, __HIP_MEMORY_SCOPE_AGENT);
            }
        } else {
            // (H) publish x_{t+1} into LDS buffer wb
#pragma unroll
            for (int i = 0; i < 16; ++i) {
                ushortT hi, lo; splitf(xv[i >> 2][i & 3], hi, lo);
                xl[wb][0][xr][xc + i] = hi; xl[wb][1][xr][xc + i] = lo;
            }
        }

        // barrier: each wave drains its own vmcnt before arriving -> all lower
        // waves' payload stores are at the coherence point; also xl/hl turnover
        __syncthreads();
        if (tid == 0)
            __hip_atomic_store(ownp, (unsigned)(t + 1),
                               __ATOMIC_RELAXED, __HIP_MEMORY_SCOPE_AGENT);

        // st stores — consumed only by k3 after this kernel; off critical path
        if (!upper) {
#pragma unroll
            for (int r4 = 0; r4 < 4; ++r4) {
                const int b = m0 + quad * 4 + r4;
                st[((size_t)b * 512 + t) * 512 + j_lane] = hn4[r4];
            }
        }
    }
}

// ---------- k3: tag logits + argmax + PAD mask (R5-identical) ----------
__global__ __launch_bounds__(256) void tag_argmax(
    const float* __restrict__ st, const ushortT* __restrict__ wtag2,
    const float* __restrict__ btag, const int* __restrict__ tok,
    float* __restrict__ out)
{
    const int wave = threadIdx.x >> 6;
    const int lane = threadIdx.x & 63;
    const int ln = lane & 15, quad = lane >> 4;
    const int mt = blockIdx.x * 4 + wave;   // 0..2047

    const float* arow = st + (size_t)(mt * 16 + ln) * 512;
    f32x4 am[4], as_[4];
#pragma unroll
    for (int ti = 0; ti < 4; ++ti) { am[ti] = (f32x4){0.f,0.f,0.f,0.f}; as_[ti] = (f32x4){0.f,0.f,0.f,0.f}; }

#pragma unroll
    for (int ks = 0; ks < 16; ++ks) {
        const int k = ks * 32 + quad * 8;
        f16x8 Ah, Al;
#pragma unroll
        for (int e = 0; e < 8; ++e) {
            const float x = arow[k + e];
            _Float16 h = (_Float16)x;
            Ah[e] = h;
            Al[e] = (_Float16)((x - (float)h) * 4096.0f);
        }
#pragma unroll
        for (int ti = 0; ti < 4; ++ti) {
            const ushortT* wr = wtag2 + (size_t)(ti * 16 + ln) * 512 + k;
            f16x8 Wh = *reinterpret_cast<const f16x8*>(wr);
            f16x8 Wl = *reinterpret_cast<const f16x8*>(wr + 32768);
            am[ti]  = MFMAH(Ah, Wh, am[ti]);
            as_[ti] = MFMAH(Ah, Wl, as_[ti]);
            as_[ti] = MFMAH(Al, Wh, as_[ti]);
        }
    }

    float vals[4][4];
#pragma unroll
    for (int ti = 0; ti < 4; ++ti) {
        const float bb = btag[ti * 16 + ln];
#pragma unroll
        for (int r = 0; r < 4; ++r) vals[ti][r] = am[ti][r] + as_[ti][r] * KSC + bb;
    }
#pragma unroll
    for (int ti = 0; ti < 4; ++ti)
#pragma unroll
        for (int r = 0; r < 4; ++r) {
            const int row = mt * 16 + quad * 4 + r;
            out[(size_t)row * 64 + ti * 16 + ln] = vals[ti][r];
        }
#pragma unroll
    for (int r = 0; r < 4; ++r) {
        float best = vals[0][r];
        int bc = ln;
#pragma unroll
        for (int ti = 1; ti < 4; ++ti) {
            const float v = vals[ti][r];
            const int c = ti * 16 + ln;
            if (v > best) { best = v; bc = c; }
        }
        for (int off = 1; off < 16; off <<= 1) {
            const float ov = __shfl_xor(best, off);
            const int oc = __shfl_xor(bc, off);
            if (ov > best || (ov == best && oc < bc)) { best = ov; bc = oc; }
        }
        if (ln == 0) {
            const int row = mt * 16 + quad * 4 + r;   // = b*512+t = token idx
            const int token = tok[row];
            const int pred = (token != 0) ? bc : 0;
            out[2097152 + (size_t)row] = (float)pred;
        }
    }
}

extern "C" void kernel_launch(void* const* d_in, const int* in_sizes, int n_in,
                              void* d_out, int out_size, void* d_ws, size_t ws_size,
                              hipStream_t stream) {
    const int*   tokens = (const int*)d_in[0];
    const float* emb    = (const float*)d_in[1];
    const float* Wih    = (const float*)d_in[2];
    const float* Whh    = (const float*)d_in[3];
    const float* bih    = (const float*)d_in[4];
    const float* bhh    = (const float*)d_in[5];
    const float* Wtag   = (const float*)d_in[6];
    const float* btag   = (const float*)d_in[7];

    char* ws = (char*)d_ws;
    unsigned* hb32  = (unsigned*)ws;                 // 262,144 B used
    ushortT*  whh2  = (ushortT*)(ws + 524288);       // 3,145,728 B
    ushortT*  wih2  = (ushortT*)(ws + 3670016);      // 1,572,864 B
    ushortT*  wtag2 = (ushortT*)(ws + 5242880);      // 131,072 B
    float*    stf   = (float*)(ws + 5373952);        // 67,108,864 B (total 72.48 MB)
    float*    out   = (float*)d_out;

    // Sync flags live in d_out's preds region (scratch during gru_rec;
    // tag_argmax rewrites every preds element afterwards). 32 flags, 128B pad.
    unsigned* flags = (unsigned*)(out + 2097152);

    split_weights<<<4736, 256, 0, stream>>>(Whh, Wih, Wtag, whh2, wih2, wtag2);
    init_ws<<<128, 256, 0, stream>>>((uint4*)ws, (uint4*)flags);
    gru_rec<<<32, 512, 0, stream>>>(tokens, emb, wih2, whh2, bih, bhh, hb32, stf, flags);
    tag_argmax<<<512, 256, 0, stream>>>(stf, wtag2, btag, tokens, out);
}